// Round 2
// baseline (6400.040 us; speedup 1.0000x reference)
//
#include <hip/hip_runtime.h>

#define NPTS   40000
#define NG     4
#define NK     64
#define ND     400
#define PT     256          // points per assign tile
#define BK     16           // d-chunk size
#define NCHUNK 25           // ND / BK
#define NTILES 157          // ceil(NPTS / PT)
#define PCH    16           // point chunks in accum
#define PPB    2500         // points per chunk (16*2500 = 40000)

// ---------------------------------------------------------------------------
// Kernel A: scores GEMM + argmax -> labels + per-tile counts.
// One block = one 256-point tile of one group. LDS ~38 KB -> 3 blocks/CU.
// ---------------------------------------------------------------------------
__global__ __launch_bounds__(256, 3)
void assign_kernel(const float* __restrict__ patches,   // [NPTS][NG][ND]
                   const float* __restrict__ cent,      // [NG][NK][ND]
                   int*   __restrict__ labels_g,        // [NG][NPTS]
                   int*   __restrict__ pcnt)            // [NG][NTILES][NK]
{
    const int g    = blockIdx.y;
    const int tile = blockIdx.x;
    const int t    = threadIdx.x;
    const int n0   = tile * PT;

    __shared__ float pT[BK][PT + 4];        // stride 260: 16B-aligned float4 rows
    __shared__ float cT[BK][NK + 4];        // stride 68
    __shared__ float xmax[8][PT];
    __shared__ int   xidx[8][PT];
    __shared__ float c2p[NK][4];
    __shared__ float c2s[NK];
    __shared__ int   cnt[NK];

    if (t < NK) cnt[t] = 0;

    // 0.5*||c_k||^2, 4 threads per cluster then combine
    {
        int k = t >> 2, j = t & 3;
        const float* c = cent + ((size_t)g * NK + k) * ND + 100 * j;
        float s = 0.0f;
        #pragma unroll
        for (int d = 0; d < 100; d += 4) {
            float4 v = *(const float4*)(c + d);
            s = fmaf(v.x, v.x, fmaf(v.y, v.y, fmaf(v.z, v.z, fmaf(v.w, v.w, s))));
        }
        c2p[k][j] = s;
    }
    __syncthreads();
    if (t < NK) c2s[t] = 0.5f * (c2p[t][0] + c2p[t][1] + c2p[t][2] + c2p[t][3]);

    const int pq = t & 31;   // owns points 4*pq..4*pq+3 and 128+4*pq..
    const int cg = t >> 5;   // owns clusters 8*cg..8*cg+7

    float acc[8][8];
    #pragma unroll
    for (int i = 0; i < 8; ++i)
        #pragma unroll
        for (int j = 0; j < 8; ++j) acc[i][j] = 0.0f;

    float4 pp[4]; float4 pc;
    #pragma unroll
    for (int s = 0; s < 4; ++s) {
        int flat = t + 256 * s, n = flat >> 2, j = flat & 3;
        int nn = n0 + n; if (nn >= NPTS) nn = NPTS - 1;
        pp[s] = *(const float4*)(patches + ((size_t)nn * NG + g) * ND + 4 * j);
    }
    {
        int k = t >> 2, j = t & 3;
        pc = *(const float4*)(cent + ((size_t)g * NK + k) * ND + 4 * j);
    }

    for (int c = 0; c < NCHUNK; ++c) {
        #pragma unroll
        for (int s = 0; s < 4; ++s) {
            int flat = t + 256 * s, n = flat >> 2, j = flat & 3;
            pT[4 * j + 0][n] = pp[s].x;
            pT[4 * j + 1][n] = pp[s].y;
            pT[4 * j + 2][n] = pp[s].z;
            pT[4 * j + 3][n] = pp[s].w;
        }
        {
            int k = t >> 2, j = t & 3;
            cT[4 * j + 0][k] = pc.x;
            cT[4 * j + 1][k] = pc.y;
            cT[4 * j + 2][k] = pc.z;
            cT[4 * j + 3][k] = pc.w;
        }
        __syncthreads();

        if (c + 1 < NCHUNK) {
            const int d0 = (c + 1) * BK;
            #pragma unroll
            for (int s = 0; s < 4; ++s) {
                int flat = t + 256 * s, n = flat >> 2, j = flat & 3;
                int nn = n0 + n; if (nn >= NPTS) nn = NPTS - 1;
                pp[s] = *(const float4*)(patches + ((size_t)nn * NG + g) * ND + d0 + 4 * j);
            }
            int k = t >> 2, j = t & 3;
            pc = *(const float4*)(cent + ((size_t)g * NK + k) * ND + d0 + 4 * j);
        }

        #pragma unroll
        for (int d = 0; d < BK; ++d) {
            float4 pa = *(const float4*)&pT[d][4 * pq];
            float4 pb = *(const float4*)&pT[d][128 + 4 * pq];
            float4 ca = *(const float4*)&cT[d][8 * cg];
            float4 cb = *(const float4*)&cT[d][8 * cg + 4];
            float pv[8] = {pa.x, pa.y, pa.z, pa.w, pb.x, pb.y, pb.z, pb.w};
            float cv[8] = {ca.x, ca.y, ca.z, ca.w, cb.x, cb.y, cb.z, cb.w};
            #pragma unroll
            for (int i = 0; i < 8; ++i)
                #pragma unroll
                for (int j = 0; j < 8; ++j)
                    acc[i][j] = fmaf(pv[i], cv[j], acc[i][j]);
        }
        __syncthreads();
    }

    // argmax: first-max tie-break ascending k (matches jnp.argmax)
    #pragma unroll
    for (int i = 0; i < 8; ++i) {
        int p = (i < 4) ? (4 * pq + i) : (128 + 4 * pq + (i - 4));
        float m = -3.402823466e+38f; int best = 8 * cg;
        #pragma unroll
        for (int j = 0; j < 8; ++j) {
            float s = acc[i][j] - c2s[8 * cg + j];
            if (s > m) { m = s; best = 8 * cg + j; }
        }
        xmax[cg][p] = m; xidx[cg][p] = best;
    }
    __syncthreads();
    {
        float m = xmax[0][t]; int best = xidx[0][t];
        #pragma unroll
        for (int u = 1; u < 8; ++u) {
            float v = xmax[u][t];
            if (v > m) { m = v; best = xidx[u][t]; }
        }
        if (n0 + t < NPTS) {
            labels_g[(size_t)g * NPTS + n0 + t] = best;
            atomicAdd(&cnt[best], 1);
        }
    }
    __syncthreads();
    if (t < NK) pcnt[((size_t)g * NTILES + tile) * NK + t] = cnt[t];
}

// ---------------------------------------------------------------------------
// Kernel B: scatter-accumulate. Block = (d-chunk of 16 floats, 2500-point
// range, group). 4.4 KB LDS -> high occupancy; patches re-read is L3-hot.
// ---------------------------------------------------------------------------
__global__ __launch_bounds__(256, 8)
void accum_kernel(const float* __restrict__ patches,    // [NPTS][NG][ND]
                  const int*   __restrict__ labels_g,   // [NG][NPTS]
                  float* __restrict__ psum)             // [NG][PCH][NK][ND]
{
    const int dchunk = blockIdx.x;
    const int pchunk = blockIdx.y;
    const int g      = blockIdx.z;
    const int t      = threadIdx.x;
    const int d0     = dchunk * BK;

    __shared__ float sums[NK][17];          // stride 17: odd -> spread banks
    for (int i = t; i < NK * 17; i += 256) (&sums[0][0])[i] = 0.0f;
    __syncthreads();

    const int q  = t & 3;                   // d-quad within the 16-float chunk
    const int pl = t >> 2;                  // 64 points per iteration
    const int n0 = pchunk * PPB;
    const int nend = n0 + PPB;

    #pragma unroll 2
    for (int n = n0 + pl; n < nend; n += 64) {
        int L = labels_g[(size_t)g * NPTS + n];
        float4 v = *(const float4*)(patches + ((size_t)n * NG + g) * ND + d0 + 4 * q);
        atomicAdd(&sums[L][4 * q + 0], v.x);
        atomicAdd(&sums[L][4 * q + 1], v.y);
        atomicAdd(&sums[L][4 * q + 2], v.z);
        atomicAdd(&sums[L][4 * q + 3], v.w);
    }
    __syncthreads();

    for (int i = t; i < NK * BK; i += 256) {
        int k = i >> 4, d = i & 15;
        psum[(((size_t)g * PCH + pchunk) * NK + k) * ND + d0 + d] = sums[k][d];
    }
}

// ---------------------------------------------------------------------------
// Update: reduce PCH partials + NTILES count partials, divide (1 if empty),
// zero clusters empty in ANY group. Block = one (g,k).
// ---------------------------------------------------------------------------
__global__ __launch_bounds__(256)
void update_kernel(const float* __restrict__ psum,
                   const int*   __restrict__ pcnt,
                   float* __restrict__ outc)             // [NG][NK][ND]
{
    const int gk = blockIdx.x;
    const int g = gk >> 6, k = gk & 63;
    const int t = threadIdx.x;

    __shared__ int cs[NG];
    if (t < NG) cs[t] = 0;
    __syncthreads();
    for (int i = t; i < NG * NTILES; i += 256) {
        int g2 = i / NTILES, tl = i - g2 * NTILES;
        atomicAdd(&cs[g2], pcnt[((size_t)g2 * NTILES + tl) * NK + k]);
    }
    __syncthreads();
    const bool bad = (cs[0] == 0) | (cs[1] == 0) | (cs[2] == 0) | (cs[3] == 0);
    const float denom = (float)(cs[g] == 0 ? 1 : cs[g]);

    for (int d = t; d < ND; d += 256) {
        float s = 0.0f;
        #pragma unroll
        for (int p = 0; p < PCH; ++p)
            s += psum[(((size_t)g * PCH + p) * NK + k) * ND + d];
        outc[(size_t)gk * ND + d] = bad ? 0.0f : (s / denom);
    }
}

extern "C" void kernel_launch(void* const* d_in, const int* in_sizes, int n_in,
                              void* d_out, int out_size, void* d_ws, size_t ws_size,
                              hipStream_t stream)
{
    const float* patches = (const float*)d_in[0];
    const float* cinit   = (const float*)d_in[1];
    float* out = (float*)d_out;

    const size_t CSZ = (size_t)NG * NK * ND;            // 102400 floats
    float* centA = (float*)d_ws;
    float* centB = centA + CSZ;
    int*   labels = (int*)(centB + CSZ);                // NG*NPTS ints
    int*   pcnt   = labels + (size_t)NG * NPTS;         // NG*NTILES*NK ints
    float* psum   = (float*)(pcnt + (size_t)NG * NTILES * NK);  // NG*PCH*NK*ND

    const float* cur = cinit;
    for (int e = 0; e < 10; ++e) {
        assign_kernel<<<dim3(NTILES, NG), 256, 0, stream>>>(patches, cur, labels, pcnt);
        accum_kernel<<<dim3(NCHUNK, PCH, NG), 256, 0, stream>>>(patches, labels, psum);
        float* nxt = (e == 9) ? out : ((e & 1) ? centB : centA);
        update_kernel<<<dim3(NG * NK), 256, 0, stream>>>(psum, pcnt, nxt);
        cur = nxt;
    }
}

// Round 3
// 3565.198 us; speedup vs baseline: 1.7951x; 1.7951x over previous
//
#include <hip/hip_runtime.h>

#define NPTS   40000
#define NG     4
#define NK     64
#define ND     400
#define PT     256          // points per assign tile
#define BK     16           // d-chunk size
#define NCHUNK 25           // ND / BK
#define NTILES 157          // ceil(NPTS / PT)
#define NSPL   16           // gather splits per cluster

// ---------------------------------------------------------------------------
// Kernel A: scores GEMM + argmax -> packed (rank<<8)|label + per-tile counts.
// ---------------------------------------------------------------------------
__global__ __launch_bounds__(256, 3)
void assign_kernel(const float* __restrict__ patches,   // [NPTS][NG][ND]
                   const float* __restrict__ cent,      // [NG][NK][ND]
                   int*   __restrict__ lr,              // [NG][NPTS] packed
                   int*   __restrict__ pcnt)            // [NG][NTILES][NK]
{
    const int g    = blockIdx.y;
    const int tile = blockIdx.x;
    const int t    = threadIdx.x;
    const int n0   = tile * PT;

    __shared__ float pT[BK][PT + 4];
    __shared__ float cT[BK][NK + 4];
    __shared__ float xmax[8][PT];
    __shared__ int   xidx[8][PT];
    __shared__ float c2p[NK][4];
    __shared__ float c2s[NK];
    __shared__ int   cnt[NK];

    if (t < NK) cnt[t] = 0;

    {
        int k = t >> 2, j = t & 3;
        const float* c = cent + ((size_t)g * NK + k) * ND + 100 * j;
        float s = 0.0f;
        #pragma unroll
        for (int d = 0; d < 100; d += 4) {
            float4 v = *(const float4*)(c + d);
            s = fmaf(v.x, v.x, fmaf(v.y, v.y, fmaf(v.z, v.z, fmaf(v.w, v.w, s))));
        }
        c2p[k][j] = s;
    }
    __syncthreads();
    if (t < NK) c2s[t] = 0.5f * (c2p[t][0] + c2p[t][1] + c2p[t][2] + c2p[t][3]);

    const int pq = t & 31;
    const int cg = t >> 5;

    float acc[8][8];
    #pragma unroll
    for (int i = 0; i < 8; ++i)
        #pragma unroll
        for (int j = 0; j < 8; ++j) acc[i][j] = 0.0f;

    float4 pp[4]; float4 pc;
    #pragma unroll
    for (int s = 0; s < 4; ++s) {
        int flat = t + 256 * s, n = flat >> 2, j = flat & 3;
        int nn = n0 + n; if (nn >= NPTS) nn = NPTS - 1;
        pp[s] = *(const float4*)(patches + ((size_t)nn * NG + g) * ND + 4 * j);
    }
    {
        int k = t >> 2, j = t & 3;
        pc = *(const float4*)(cent + ((size_t)g * NK + k) * ND + 4 * j);
    }

    for (int c = 0; c < NCHUNK; ++c) {
        #pragma unroll
        for (int s = 0; s < 4; ++s) {
            int flat = t + 256 * s, n = flat >> 2, j = flat & 3;
            pT[4 * j + 0][n] = pp[s].x;
            pT[4 * j + 1][n] = pp[s].y;
            pT[4 * j + 2][n] = pp[s].z;
            pT[4 * j + 3][n] = pp[s].w;
        }
        {
            int k = t >> 2, j = t & 3;
            cT[4 * j + 0][k] = pc.x;
            cT[4 * j + 1][k] = pc.y;
            cT[4 * j + 2][k] = pc.z;
            cT[4 * j + 3][k] = pc.w;
        }
        __syncthreads();

        if (c + 1 < NCHUNK) {
            const int d0 = (c + 1) * BK;
            #pragma unroll
            for (int s = 0; s < 4; ++s) {
                int flat = t + 256 * s, n = flat >> 2, j = flat & 3;
                int nn = n0 + n; if (nn >= NPTS) nn = NPTS - 1;
                pp[s] = *(const float4*)(patches + ((size_t)nn * NG + g) * ND + d0 + 4 * j);
            }
            int k = t >> 2, j = t & 3;
            pc = *(const float4*)(cent + ((size_t)g * NK + k) * ND + d0 + 4 * j);
        }

        #pragma unroll
        for (int d = 0; d < BK; ++d) {
            float4 pa = *(const float4*)&pT[d][4 * pq];
            float4 pb = *(const float4*)&pT[d][128 + 4 * pq];
            float4 ca = *(const float4*)&cT[d][8 * cg];
            float4 cb = *(const float4*)&cT[d][8 * cg + 4];
            float pv[8] = {pa.x, pa.y, pa.z, pa.w, pb.x, pb.y, pb.z, pb.w};
            float cv[8] = {ca.x, ca.y, ca.z, ca.w, cb.x, cb.y, cb.z, cb.w};
            #pragma unroll
            for (int i = 0; i < 8; ++i)
                #pragma unroll
                for (int j = 0; j < 8; ++j)
                    acc[i][j] = fmaf(pv[i], cv[j], acc[i][j]);
        }
        __syncthreads();
    }

    #pragma unroll
    for (int i = 0; i < 8; ++i) {
        int p = (i < 4) ? (4 * pq + i) : (128 + 4 * pq + (i - 4));
        float m = -3.402823466e+38f; int best = 8 * cg;
        #pragma unroll
        for (int j = 0; j < 8; ++j) {
            float s = acc[i][j] - c2s[8 * cg + j];
            if (s > m) { m = s; best = 8 * cg + j; }
        }
        xmax[cg][p] = m; xidx[cg][p] = best;
    }
    __syncthreads();
    {
        float m = xmax[0][t]; int best = xidx[0][t];
        #pragma unroll
        for (int u = 1; u < 8; ++u) {
            float v = xmax[u][t];
            if (v > m) { m = v; best = xidx[u][t]; }
        }
        if (n0 + t < NPTS) {
            int r = atomicAdd(&cnt[best], 1);       // within-tile rank, free
            lr[(size_t)g * NPTS + n0 + t] = (r << 8) | best;
        }
    }
    __syncthreads();
    if (t < NK) pcnt[((size_t)g * NTILES + tile) * NK + t] = cnt[t];
}

// ---------------------------------------------------------------------------
// Scan: per group, cluster totals + cluster base offsets + per-tile bases.
// ---------------------------------------------------------------------------
__global__ __launch_bounds__(256)
void scan_kernel(const int* __restrict__ pcnt,     // [NG][NTILES][NK]
                 int* __restrict__ tilebase,       // [NG][NTILES][NK]
                 int* __restrict__ cbase,          // [NG][NK]
                 int* __restrict__ counts)         // [NG][NK]
{
    const int g = blockIdx.x;
    const int t = threadIdx.x;
    __shared__ int cnt_tk[NTILES * NK];            // 40 KB
    __shared__ int totals[NK];
    __shared__ int kbase[NK];

    for (int i = t; i < NTILES * NK; i += 256)
        cnt_tk[i] = pcnt[(size_t)g * NTILES * NK + i];
    __syncthreads();

    if (t < NK) {
        int s = 0;
        for (int tl = 0; tl < NTILES; ++tl) s += cnt_tk[tl * NK + t];
        totals[t] = s;
    }
    __syncthreads();
    if (t == 0) {
        int run = 0;
        for (int k = 0; k < NK; ++k) { kbase[k] = run; run += totals[k]; }
    }
    __syncthreads();
    if (t < NK) {
        counts[g * NK + t] = totals[t];
        cbase[g * NK + t]  = kbase[t];
        int run = kbase[t];
        for (int tl = 0; tl < NTILES; ++tl) {
            tilebase[((size_t)g * NTILES + tl) * NK + t] = run;
            run += cnt_tk[tl * NK + t];
        }
    }
}

// ---------------------------------------------------------------------------
// Scatter: order[g][tilebase + rank] = n. No atomics.
// ---------------------------------------------------------------------------
__global__ __launch_bounds__(256)
void scatter_kernel(const int* __restrict__ lr,        // [NG][NPTS]
                    const int* __restrict__ tilebase,  // [NG][NTILES][NK]
                    int* __restrict__ order)           // [NG][NPTS]
{
    const int tile = blockIdx.x, g = blockIdx.y, t = threadIdx.x;
    const int n = tile * PT + t;
    if (n < NPTS) {
        int packed = lr[(size_t)g * NPTS + n];
        int L = packed & 63, r = packed >> 8;
        order[(size_t)g * NPTS + tilebase[((size_t)g * NTILES + tile) * NK + L] + r] = n;
    }
}

// ---------------------------------------------------------------------------
// Gather: block = (split, k, g). 5 points x 100 lanes per iter, register acc,
// whole contiguous 1600B rows -> streaming-friendly, no hot-loop atomics.
// ---------------------------------------------------------------------------
__global__ __launch_bounds__(512, 2)
void gather_kernel(const float* __restrict__ patches,  // [NPTS][NG][ND]
                   const int*   __restrict__ order,    // [NG][NPTS]
                   const int*   __restrict__ cbase,    // [NG][NK]
                   const int*   __restrict__ counts,   // [NG][NK]
                   float* __restrict__ psum)           // [NG][NK][NSPL][ND]
{
    const int s = blockIdx.x, k = blockIdx.y, g = blockIdx.z;
    const int t = threadIdx.x;
    const int base = cbase[g * NK + k];
    const int cnt  = counts[g * NK + k];
    const int start = base + (cnt * s) / NSPL;
    const int end   = base + (cnt * (s + 1)) / NSPL;

    const int slot = t / 100;          // 0..4 active (t<500)
    const int q    = t - slot * 100;   // d-quad 0..99

    float4 acc = make_float4(0.f, 0.f, 0.f, 0.f);
    if (t < 500) {
        const int* ord = order + (size_t)g * NPTS;
        #pragma unroll 4
        for (int i = start + slot; i < end; i += 5) {
            int n = ord[i];
            float4 v = *(const float4*)(patches + ((size_t)n * NG + g) * ND + 4 * q);
            acc.x += v.x; acc.y += v.y; acc.z += v.z; acc.w += v.w;
        }
    }

    __shared__ float sums[ND];
    for (int i = t; i < ND; i += 512) sums[i] = 0.0f;
    __syncthreads();
    if (t < 500) {
        atomicAdd(&sums[4 * q + 0], acc.x);
        atomicAdd(&sums[4 * q + 1], acc.y);
        atomicAdd(&sums[4 * q + 2], acc.z);
        atomicAdd(&sums[4 * q + 3], acc.w);
    }
    __syncthreads();
    if (t < 100) {
        float* dst = psum + (((size_t)(g * NK + k)) * NSPL + s) * ND + 4 * t;
        *(float4*)dst = *(const float4*)&sums[4 * t];
    }
}

// ---------------------------------------------------------------------------
// Update: reduce NSPL partials, divide (1 if empty), zero clusters empty in
// ANY group.
// ---------------------------------------------------------------------------
__global__ __launch_bounds__(128)
void update_kernel(const float* __restrict__ psum,     // [NG][NK][NSPL][ND]
                   const int*   __restrict__ counts,   // [NG][NK]
                   float* __restrict__ outc)           // [NG][NK][ND]
{
    const int gk = blockIdx.x;
    const int g = gk >> 6, k = gk & 63;
    const int t = threadIdx.x;

    const bool bad = (counts[0 * NK + k] == 0) | (counts[1 * NK + k] == 0) |
                     (counts[2 * NK + k] == 0) | (counts[3 * NK + k] == 0);
    const int  c  = counts[g * NK + k];
    const float inv = 1.0f / (float)(c == 0 ? 1 : c);

    if (t < 100) {
        float4 s = make_float4(0.f, 0.f, 0.f, 0.f);
        const float* p = psum + ((size_t)gk * NSPL) * ND + 4 * t;
        #pragma unroll
        for (int sp = 0; sp < NSPL; ++sp) {
            float4 v = *(const float4*)(p + (size_t)sp * ND);
            s.x += v.x; s.y += v.y; s.z += v.z; s.w += v.w;
        }
        float4 o;
        o.x = bad ? 0.0f : s.x * inv;
        o.y = bad ? 0.0f : s.y * inv;
        o.z = bad ? 0.0f : s.z * inv;
        o.w = bad ? 0.0f : s.w * inv;
        *(float4*)(outc + (size_t)gk * ND + 4 * t) = o;
    }
}

extern "C" void kernel_launch(void* const* d_in, const int* in_sizes, int n_in,
                              void* d_out, int out_size, void* d_ws, size_t ws_size,
                              hipStream_t stream)
{
    const float* patches = (const float*)d_in[0];
    const float* cinit   = (const float*)d_in[1];
    float* out = (float*)d_out;

    const size_t CSZ = (size_t)NG * NK * ND;              // 102400
    float* centA = (float*)d_ws;
    float* centB = centA + CSZ;
    int* lr       = (int*)(centB + CSZ);                  // NG*NPTS
    int* pcnt     = lr + (size_t)NG * NPTS;               // NG*NTILES*NK
    int* tilebase = pcnt + (size_t)NG * NTILES * NK;      // NG*NTILES*NK
    int* cbase    = tilebase + (size_t)NG * NTILES * NK;  // NG*NK
    int* counts   = cbase + NG * NK;                      // NG*NK
    int* order    = counts + NG * NK;                     // NG*NPTS
    float* psum   = (float*)(order + (size_t)NG * NPTS);  // NG*NK*NSPL*ND

    const float* cur = cinit;
    for (int e = 0; e < 10; ++e) {
        assign_kernel<<<dim3(NTILES, NG), 256, 0, stream>>>(patches, cur, lr, pcnt);
        scan_kernel<<<NG, 256, 0, stream>>>(pcnt, tilebase, cbase, counts);
        scatter_kernel<<<dim3(NTILES, NG), 256, 0, stream>>>(lr, tilebase, order);
        gather_kernel<<<dim3(NSPL, NK, NG), 512, 0, stream>>>(patches, order, cbase, counts, psum);
        float* nxt = (e == 9) ? out : ((e & 1) ? centB : centA);
        update_kernel<<<dim3(NG * NK), 128, 0, stream>>>(psum, counts, nxt);
        cur = nxt;
    }
}

// Round 4
// 2116.768 us; speedup vs baseline: 3.0235x; 1.6843x over previous
//
#include <hip/hip_runtime.h>

#define NPTS   40000
#define NG     4
#define NK     64
#define ND     400
#define PT     256          // points per assign tile
#define BK     16           // d-chunk size
#define NCHUNK 25           // ND / BK
#define NTILES 157          // ceil(NPTS / PT)
#define NSPL   16           // gather splits per cluster

// ---------------------------------------------------------------------------
// Kernel A: scores GEMM + argmax -> packed (rank<<8)|label + per-tile counts.
// NOTE: plain __launch_bounds__(256) — the (256,3) min-waves hint made the
// allocator spill acc[8][8] to scratch (VGPR 164->84, 408 MB scratch writes).
// ---------------------------------------------------------------------------
__global__ __launch_bounds__(256)
void assign_kernel(const float* __restrict__ patches,   // [NPTS][NG][ND]
                   const float* __restrict__ cent,      // [NG][NK][ND]
                   int*   __restrict__ lr,              // [NG][NPTS] packed
                   int*   __restrict__ pcnt)            // [NG][NTILES][NK]
{
    const int g    = blockIdx.y;
    const int tile = blockIdx.x;
    const int t    = threadIdx.x;
    const int n0   = tile * PT;

    __shared__ float pT[BK][PT + 4];
    __shared__ float cT[BK][NK + 4];
    __shared__ float xmax[8][PT];
    __shared__ int   xidx[8][PT];
    __shared__ float c2p[NK][4];
    __shared__ float c2s[NK];
    __shared__ int   cnt[NK];

    if (t < NK) cnt[t] = 0;

    {
        int k = t >> 2, j = t & 3;
        const float* c = cent + ((size_t)g * NK + k) * ND + 100 * j;
        float s = 0.0f;
        #pragma unroll
        for (int d = 0; d < 100; d += 4) {
            float4 v = *(const float4*)(c + d);
            s = fmaf(v.x, v.x, fmaf(v.y, v.y, fmaf(v.z, v.z, fmaf(v.w, v.w, s))));
        }
        c2p[k][j] = s;
    }
    __syncthreads();
    if (t < NK) c2s[t] = 0.5f * (c2p[t][0] + c2p[t][1] + c2p[t][2] + c2p[t][3]);

    const int pq = t & 31;
    const int cg = t >> 5;

    float acc[8][8];
    #pragma unroll
    for (int i = 0; i < 8; ++i)
        #pragma unroll
        for (int j = 0; j < 8; ++j) acc[i][j] = 0.0f;

    float4 pp[4]; float4 pc;
    #pragma unroll
    for (int s = 0; s < 4; ++s) {
        int flat = t + 256 * s, n = flat >> 2, j = flat & 3;
        int nn = n0 + n; if (nn >= NPTS) nn = NPTS - 1;
        pp[s] = *(const float4*)(patches + ((size_t)nn * NG + g) * ND + 4 * j);
    }
    {
        int k = t >> 2, j = t & 3;
        pc = *(const float4*)(cent + ((size_t)g * NK + k) * ND + 4 * j);
    }

    for (int c = 0; c < NCHUNK; ++c) {
        #pragma unroll
        for (int s = 0; s < 4; ++s) {
            int flat = t + 256 * s, n = flat >> 2, j = flat & 3;
            pT[4 * j + 0][n] = pp[s].x;
            pT[4 * j + 1][n] = pp[s].y;
            pT[4 * j + 2][n] = pp[s].z;
            pT[4 * j + 3][n] = pp[s].w;
        }
        {
            int k = t >> 2, j = t & 3;
            cT[4 * j + 0][k] = pc.x;
            cT[4 * j + 1][k] = pc.y;
            cT[4 * j + 2][k] = pc.z;
            cT[4 * j + 3][k] = pc.w;
        }
        __syncthreads();

        if (c + 1 < NCHUNK) {
            const int d0 = (c + 1) * BK;
            #pragma unroll
            for (int s = 0; s < 4; ++s) {
                int flat = t + 256 * s, n = flat >> 2, j = flat & 3;
                int nn = n0 + n; if (nn >= NPTS) nn = NPTS - 1;
                pp[s] = *(const float4*)(patches + ((size_t)nn * NG + g) * ND + d0 + 4 * j);
            }
            int k = t >> 2, j = t & 3;
            pc = *(const float4*)(cent + ((size_t)g * NK + k) * ND + d0 + 4 * j);
        }

        #pragma unroll
        for (int d = 0; d < BK; ++d) {
            float4 pa = *(const float4*)&pT[d][4 * pq];
            float4 pb = *(const float4*)&pT[d][128 + 4 * pq];
            float4 ca = *(const float4*)&cT[d][8 * cg];
            float4 cb = *(const float4*)&cT[d][8 * cg + 4];
            float pv[8] = {pa.x, pa.y, pa.z, pa.w, pb.x, pb.y, pb.z, pb.w};
            float cv[8] = {ca.x, ca.y, ca.z, ca.w, cb.x, cb.y, cb.z, cb.w};
            #pragma unroll
            for (int i = 0; i < 8; ++i)
                #pragma unroll
                for (int j = 0; j < 8; ++j)
                    acc[i][j] = fmaf(pv[i], cv[j], acc[i][j]);
        }
        __syncthreads();
    }

    #pragma unroll
    for (int i = 0; i < 8; ++i) {
        int p = (i < 4) ? (4 * pq + i) : (128 + 4 * pq + (i - 4));
        float m = -3.402823466e+38f; int best = 8 * cg;
        #pragma unroll
        for (int j = 0; j < 8; ++j) {
            float s = acc[i][j] - c2s[8 * cg + j];
            if (s > m) { m = s; best = 8 * cg + j; }
        }
        xmax[cg][p] = m; xidx[cg][p] = best;
    }
    __syncthreads();
    {
        float m = xmax[0][t]; int best = xidx[0][t];
        #pragma unroll
        for (int u = 1; u < 8; ++u) {
            float v = xmax[u][t];
            if (v > m) { m = v; best = xidx[u][t]; }
        }
        if (n0 + t < NPTS) {
            int r = atomicAdd(&cnt[best], 1);       // within-tile rank, free
            lr[(size_t)g * NPTS + n0 + t] = (r << 8) | best;
        }
    }
    __syncthreads();
    if (t < NK) pcnt[((size_t)g * NTILES + tile) * NK + t] = cnt[t];
}

// ---------------------------------------------------------------------------
// Scan: per group, cluster totals + cluster base offsets + per-tile bases.
// ---------------------------------------------------------------------------
__global__ __launch_bounds__(256)
void scan_kernel(const int* __restrict__ pcnt,     // [NG][NTILES][NK]
                 int* __restrict__ tilebase,       // [NG][NTILES][NK]
                 int* __restrict__ cbase,          // [NG][NK]
                 int* __restrict__ counts)         // [NG][NK]
{
    const int g = blockIdx.x;
    const int t = threadIdx.x;
    __shared__ int cnt_tk[NTILES * NK];            // 40 KB
    __shared__ int totals[NK];
    __shared__ int kbase[NK];

    for (int i = t; i < NTILES * NK; i += 256)
        cnt_tk[i] = pcnt[(size_t)g * NTILES * NK + i];
    __syncthreads();

    if (t < NK) {
        int s = 0;
        for (int tl = 0; tl < NTILES; ++tl) s += cnt_tk[tl * NK + t];
        totals[t] = s;
    }
    __syncthreads();
    if (t == 0) {
        int run = 0;
        for (int k = 0; k < NK; ++k) { kbase[k] = run; run += totals[k]; }
    }
    __syncthreads();
    if (t < NK) {
        counts[g * NK + t] = totals[t];
        cbase[g * NK + t]  = kbase[t];
        int run = kbase[t];
        for (int tl = 0; tl < NTILES; ++tl) {
            tilebase[((size_t)g * NTILES + tl) * NK + t] = run;
            run += cnt_tk[tl * NK + t];
        }
    }
}

// ---------------------------------------------------------------------------
// Scatter: order[g][tilebase + rank] = n. No atomics.
// ---------------------------------------------------------------------------
__global__ __launch_bounds__(256)
void scatter_kernel(const int* __restrict__ lr,        // [NG][NPTS]
                    const int* __restrict__ tilebase,  // [NG][NTILES][NK]
                    int* __restrict__ order)           // [NG][NPTS]
{
    const int tile = blockIdx.x, g = blockIdx.y, t = threadIdx.x;
    const int n = tile * PT + t;
    if (n < NPTS) {
        int packed = lr[(size_t)g * NPTS + n];
        int L = packed & 63, r = packed >> 8;
        order[(size_t)g * NPTS + tilebase[((size_t)g * NTILES + tile) * NK + L] + r] = n;
    }
}

// ---------------------------------------------------------------------------
// Gather: block = (split, k, g). 5 points x 100 lanes per iter, register acc,
// whole contiguous 1600B rows -> streaming-friendly, no hot-loop atomics.
// ---------------------------------------------------------------------------
__global__ __launch_bounds__(512, 2)
void gather_kernel(const float* __restrict__ patches,  // [NPTS][NG][ND]
                   const int*   __restrict__ order,    // [NG][NPTS]
                   const int*   __restrict__ cbase,    // [NG][NK]
                   const int*   __restrict__ counts,   // [NG][NK]
                   float* __restrict__ psum)           // [NG][NK][NSPL][ND]
{
    const int s = blockIdx.x, k = blockIdx.y, g = blockIdx.z;
    const int t = threadIdx.x;
    const int base = cbase[g * NK + k];
    const int cnt  = counts[g * NK + k];
    const int start = base + (cnt * s) / NSPL;
    const int end   = base + (cnt * (s + 1)) / NSPL;

    const int slot = t / 100;          // 0..4 active (t<500)
    const int q    = t - slot * 100;   // d-quad 0..99

    float4 acc = make_float4(0.f, 0.f, 0.f, 0.f);
    if (t < 500) {
        const int* ord = order + (size_t)g * NPTS;
        #pragma unroll 4
        for (int i = start + slot; i < end; i += 5) {
            int n = ord[i];
            float4 v = *(const float4*)(patches + ((size_t)n * NG + g) * ND + 4 * q);
            acc.x += v.x; acc.y += v.y; acc.z += v.z; acc.w += v.w;
        }
    }

    __shared__ float sums[ND];
    for (int i = t; i < ND; i += 512) sums[i] = 0.0f;
    __syncthreads();
    if (t < 500) {
        atomicAdd(&sums[4 * q + 0], acc.x);
        atomicAdd(&sums[4 * q + 1], acc.y);
        atomicAdd(&sums[4 * q + 2], acc.z);
        atomicAdd(&sums[4 * q + 3], acc.w);
    }
    __syncthreads();
    if (t < 100) {
        float* dst = psum + (((size_t)(g * NK + k)) * NSPL + s) * ND + 4 * t;
        *(float4*)dst = *(const float4*)&sums[4 * t];
    }
}

// ---------------------------------------------------------------------------
// Update: reduce NSPL partials, divide (1 if empty), zero clusters empty in
// ANY group.
// ---------------------------------------------------------------------------
__global__ __launch_bounds__(128)
void update_kernel(const float* __restrict__ psum,     // [NG][NK][NSPL][ND]
                   const int*   __restrict__ counts,   // [NG][NK]
                   float* __restrict__ outc)           // [NG][NK][ND]
{
    const int gk = blockIdx.x;
    const int g = gk >> 6, k = gk & 63;
    const int t = threadIdx.x;

    const bool bad = (counts[0 * NK + k] == 0) | (counts[1 * NK + k] == 0) |
                     (counts[2 * NK + k] == 0) | (counts[3 * NK + k] == 0);
    const int  c  = counts[g * NK + k];
    const float inv = 1.0f / (float)(c == 0 ? 1 : c);

    if (t < 100) {
        float4 s = make_float4(0.f, 0.f, 0.f, 0.f);
        const float* p = psum + ((size_t)gk * NSPL) * ND + 4 * t;
        #pragma unroll
        for (int sp = 0; sp < NSPL; ++sp) {
            float4 v = *(const float4*)(p + (size_t)sp * ND);
            s.x += v.x; s.y += v.y; s.z += v.z; s.w += v.w;
        }
        float4 o;
        o.x = bad ? 0.0f : s.x * inv;
        o.y = bad ? 0.0f : s.y * inv;
        o.z = bad ? 0.0f : s.z * inv;
        o.w = bad ? 0.0f : s.w * inv;
        *(float4*)(outc + (size_t)gk * ND + 4 * t) = o;
    }
}

extern "C" void kernel_launch(void* const* d_in, const int* in_sizes, int n_in,
                              void* d_out, int out_size, void* d_ws, size_t ws_size,
                              hipStream_t stream)
{
    const float* patches = (const float*)d_in[0];
    const float* cinit   = (const float*)d_in[1];
    float* out = (float*)d_out;

    const size_t CSZ = (size_t)NG * NK * ND;              // 102400
    float* centA = (float*)d_ws;
    float* centB = centA + CSZ;
    int* lr       = (int*)(centB + CSZ);                  // NG*NPTS
    int* pcnt     = lr + (size_t)NG * NPTS;               // NG*NTILES*NK
    int* tilebase = pcnt + (size_t)NG * NTILES * NK;      // NG*NTILES*NK
    int* cbase    = tilebase + (size_t)NG * NTILES * NK;  // NG*NK
    int* counts   = cbase + NG * NK;                      // NG*NK
    int* order    = counts + NG * NK;                     // NG*NPTS
    float* psum   = (float*)(order + (size_t)NG * NPTS);  // NG*NK*NSPL*ND

    const float* cur = cinit;
    for (int e = 0; e < 10; ++e) {
        assign_kernel<<<dim3(NTILES, NG), 256, 0, stream>>>(patches, cur, lr, pcnt);
        scan_kernel<<<NG, 256, 0, stream>>>(pcnt, tilebase, cbase, counts);
        scatter_kernel<<<dim3(NTILES, NG), 256, 0, stream>>>(lr, tilebase, order);
        gather_kernel<<<dim3(NSPL, NK, NG), 512, 0, stream>>>(patches, order, cbase, counts, psum);
        float* nxt = (e == 9) ? out : ((e & 1) ? centB : centA);
        update_kernel<<<dim3(NG * NK), 128, 0, stream>>>(psum, counts, nxt);
        cur = nxt;
    }
}